// Round 6
// baseline (370.461 us; speedup 1.0000x reference)
//
#include <hip/hip_runtime.h>

#define NUM_LEVELS 16
#define LOG2_HASHMAP 19
#define TABLE_SIZE (1u << LOG2_HASHMAP)
#define PPT 8   // points per thread in the gather stage

typedef unsigned long long u64;
typedef unsigned long long u64x2 __attribute__((ext_vector_type(2)));  // native vec: OK for nontemporal builtins

// ---------------- Stage 0: pack fixed-point coords -------------------------
// wx = (u32)(x*2^19): multiply by power of 2 is EXACT in f32 (exponent shift),
// so wx <= 524287 always (x < 1.0) and wx>>(15-l) == trunc(x*16*2^l) by the
// floor-nesting identity -> bit-identical to the reference per level.
// Packs 3x19 bits into one u64: per-level coord traffic 24->16 MB.
__global__ __launch_bounds__(256) void pack_kernel(
    const float* __restrict__ xyz, u64* __restrict__ w, int n_points)
{
    int n = blockIdx.x * 256 + threadIdx.x;
    if (n >= n_points) return;
    float x = xyz[n * 3 + 0];
    float y = xyz[n * 3 + 1];
    float z = xyz[n * 3 + 2];
    u64 wx = (unsigned)(x * 524288.0f);
    u64 wy = (unsigned)(y * 524288.0f);
    u64 wz = (unsigned)(z * 524288.0f);
    w[n] = wx | (wy << 19) | (wz << 38);
}

// ---------------- Stage 1: XCD-pinned gather, 8 points/thread --------------
// blockIdx.x % 8 == XCD. XCD x does level x then x+8 -> one 4 MB table
// resident per XCD L2 at a time (confirmed by FETCH drop in r3).
// Rounds 3+4 showed time is invariant to traffic and MLP: bound by the
// divergent-gather service rate (~4.5 cyc/lane). Residual fix here: the
// coord stream is read NON-TEMPORALLY (zero reuse within a pass) so it
// doesn't evict table lines from L2.
__global__ __launch_bounds__(256) void gather_kernel_w(
    const u64* __restrict__ w,
    const float* __restrict__ tables,
    u64* __restrict__ ws,
    int n_points, int blocks_per_level, int stride_pts)
{
    int b     = blockIdx.x;
    int xcd   = b & 7;
    int j     = b >> 3;
    int phase = (j >= blocks_per_level) ? 1 : 0;
    int l     = xcd + (phase << 3);
    int jj    = j - phase * blocks_per_level;
    int base  = jj * 256 + (int)threadIdx.x;

    const u64* tbl = (const u64*)tables + ((size_t)l << LOG2_HASHMAP);
    u64* wsl = ws + (size_t)l * n_points;
    int shift = 15 - l;

    unsigned hh[PPT];
    int      nn[PPT];
    bool     ok[PPT];
#pragma unroll
    for (int s = 0; s < PPT; ++s) {
        int n = base + s * stride_pts;        // grid-stride: coalesced
        nn[s] = n;
        ok[s] = (n < n_points);
        u64 wp = __builtin_nontemporal_load(w + (ok[s] ? n : 0));
        unsigned wx = (unsigned)(wp & 0x7FFFFu) >> shift;
        unsigned wy = (unsigned)((wp >> 19) & 0x7FFFFu) >> shift;
        unsigned wz = (unsigned)((wp >> 38) & 0x7FFFFu) >> shift;
        // uint32 wraparound preserves low 19 bits of the int64 hash.
        hh[s] = (wx ^ (wy * 2654435761u) ^ (wz * 805459861u)) & (TABLE_SIZE - 1u);
    }

    u64 f[PPT];
#pragma unroll
    for (int s = 0; s < PPT; ++s)             // 8 independent gathers in flight
        f[s] = tbl[hh[s]];

#pragma unroll
    for (int s = 0; s < PPT; ++s)
        if (ok[s])
            __builtin_nontemporal_store(f[s], wsl + nn[s]);
}

// Unpacked variant (used when ws lacks room for the w array).
__global__ __launch_bounds__(256) void gather_kernel_xyz(
    const float* __restrict__ xyz,
    const float* __restrict__ tables,
    u64* __restrict__ ws,
    int n_points, int blocks_per_level, int stride_pts)
{
    int b     = blockIdx.x;
    int xcd   = b & 7;
    int j     = b >> 3;
    int phase = (j >= blocks_per_level) ? 1 : 0;
    int l     = xcd + (phase << 3);
    int jj    = j - phase * blocks_per_level;
    int base  = jj * 256 + (int)threadIdx.x;

    const u64* tbl = (const u64*)tables + ((size_t)l << LOG2_HASHMAP);
    u64* wsl = ws + (size_t)l * n_points;
    int shift = 15 - l;

    unsigned hh[PPT];
    int      nn[PPT];
    bool     ok[PPT];
#pragma unroll
    for (int s = 0; s < PPT; ++s) {
        int n = base + s * stride_pts;
        nn[s] = n;
        ok[s] = (n < n_points);
        int ncl = ok[s] ? n : 0;
        float x = xyz[ncl * 3 + 0];
        float y = xyz[ncl * 3 + 1];
        float z = xyz[ncl * 3 + 2];
        unsigned wx = (unsigned)(x * 524288.0f) >> shift;
        unsigned wy = (unsigned)(y * 524288.0f) >> shift;
        unsigned wz = (unsigned)(z * 524288.0f) >> shift;
        hh[s] = (wx ^ (wy * 2654435761u) ^ (wz * 805459861u)) & (TABLE_SIZE - 1u);
    }
    u64 f[PPT];
#pragma unroll
    for (int s = 0; s < PPT; ++s) f[s] = tbl[hh[s]];
#pragma unroll
    for (int s = 0; s < PPT; ++s)
        if (ok[s]) __builtin_nontemporal_store(f[s], wsl + nn[s]);
}

// ---------------- Stage 2: transpose ws[16][N] -> out[N][16] ----------------
// 16B-vectorized both sides. Level-major LDS tile: 16B contiguous ds_writes
// (2-way conflict = free); store phase reads 2 rows per lane, bank pattern
// (4*lp + 2*n) mod 32 -> exactly 2 lanes/bank = free.
__global__ __launch_bounds__(256) void transpose_kernel(
    const u64* __restrict__ ws,
    u64* __restrict__ out,
    int n_points)
{
    __shared__ u64 tile[NUM_LEVELS][129];   // [level][point], +1 u64 pad
    int n0 = blockIdx.x * 128;

    // Load: 16 levels x 64 point-pairs; lane reads u64x2 (2 consecutive
    // points, one level) -> coalesced 16B global reads.
    for (int i = threadIdx.x; i < 64 * NUM_LEVELS; i += 256) {
        int l  = i >> 6;
        int np = (i & 63) << 1;
        int gn = n0 + np;
        u64 a = 0, bb = 0;
        if (gn + 1 < n_points) {
            u64x2 v = __builtin_nontemporal_load(
                (const u64x2*)(ws + (size_t)l * n_points + gn));
            a = v.x; bb = v.y;
        } else if (gn < n_points) {
            a = __builtin_nontemporal_load(ws + (size_t)l * n_points + gn);
        }
        tile[l][np]     = a;
        tile[l][np + 1] = bb;
    }
    __syncthreads();

    // Store: lane handles (point n, level pair lp) -> 16B contiguous out write.
    for (int i = threadIdx.x; i < 128 * (NUM_LEVELS / 2); i += 256) {
        int n  = i >> 3;
        int lp = i & 7;
        if (n0 + n < n_points) {
            u64x2 v;
            v.x = tile[2 * lp][n];
            v.y = tile[2 * lp + 1][n];
            __builtin_nontemporal_store(
                v, (u64x2*)(out + ((size_t)(n0 + n) * NUM_LEVELS + 2 * lp)));
        }
    }
}

// ---------------- Fallback (round-1 kernel) if ws too small ----------------
__global__ __launch_bounds__(256) void fused_kernel(
    const float* __restrict__ xyz,
    const float* __restrict__ tables,
    u64* __restrict__ out,
    int n_points)
{
    int tid = blockIdx.x * blockDim.x + threadIdx.x;
    int n = tid >> 4;
    int l = tid & 15;
    if (n >= n_points) return;
    float x = xyz[n * 3 + 0], y = xyz[n * 3 + 1], z = xyz[n * 3 + 2];
    float res = (float)(16u << l);
    unsigned ix = (unsigned)(x * res);
    unsigned iy = (unsigned)(y * res);
    unsigned iz = (unsigned)(z * res);
    unsigned h = (ix ^ (iy * 2654435761u) ^ (iz * 805459861u)) & (TABLE_SIZE - 1u);
    u64 f = *((const u64*)tables + (((size_t)l << LOG2_HASHMAP) + h));
    out[(size_t)n * NUM_LEVELS + l] = f;
}

extern "C" void kernel_launch(void* const* d_in, const int* in_sizes, int n_in,
                              void* d_out, int out_size, void* d_ws, size_t ws_size,
                              hipStream_t stream) {
    const float* xyz    = (const float*)d_in[0];
    const float* tables = (const float*)d_in[1];

    int n_points = in_sizes[0] / 3;
    size_t ws_main = (size_t)n_points * NUM_LEVELS * sizeof(u64);
    size_t ws_pack = ws_main + (size_t)n_points * sizeof(u64);

    if (ws_size >= ws_main) {
        int blocks_per_level = (n_points + 256 * PPT - 1) / (256 * PPT);
        int stride_pts = blocks_per_level * 256;
        int grid1 = blocks_per_level * NUM_LEVELS;   // divisible by 8

        if (ws_size >= ws_pack) {
            u64* w = (u64*)d_ws + (size_t)n_points * NUM_LEVELS;
            pack_kernel<<<(n_points + 255) / 256, 256, 0, stream>>>(xyz, w, n_points);
            gather_kernel_w<<<grid1, 256, 0, stream>>>(
                w, tables, (u64*)d_ws, n_points, blocks_per_level, stride_pts);
        } else {
            gather_kernel_xyz<<<grid1, 256, 0, stream>>>(
                xyz, tables, (u64*)d_ws, n_points, blocks_per_level, stride_pts);
        }

        int grid2 = (n_points + 127) / 128;
        transpose_kernel<<<grid2, 256, 0, stream>>>(
            (const u64*)d_ws, (u64*)d_out, n_points);
    } else {
        int total = n_points * NUM_LEVELS;
        int grid = (total + 255) / 256;
        fused_kernel<<<grid, 256, 0, stream>>>(xyz, tables, (u64*)d_out, n_points);
    }
}

// Round 7
// 326.421 us; speedup vs baseline: 1.1349x; 1.1349x over previous
//
#include <hip/hip_runtime.h>

#define NUM_LEVELS 16
#define LOG2_HASHMAP 19
#define TABLE_SIZE (1u << LOG2_HASHMAP)
#define PPT 8   // points per thread in the gather stage

typedef unsigned long long u64;
typedef unsigned long long u64x2 __attribute__((ext_vector_type(2)));

// ---------------- Stage 1: XCD-pinned gather, 8 points/thread --------------
// blockIdx.x % 8 == XCD. XCD x does level x then x+8 -> one 4 MB table
// resident per XCD L2 at a time. Probe history:
//   r3: traffic -12% -> time null      (not fetch-bound)
//   r4: 8x MLP, 8x fewer blocks -> null (not latency/churn-bound)
//   r6: nt coord loads, fetch -47% -> time +14% (cache-absorbed re-reads
//       were free; nt bypass put them on the critical path)
// Conclusion: bound by L2 random-request service (~17 G req/s/XCD).
// This version: cached xyz loads (L3 absorbs the 16x re-reads), nt ONLY on
// the ws write stream.
__global__ __launch_bounds__(256) void gather_kernel_xyz(
    const float* __restrict__ xyz,
    const float* __restrict__ tables,
    u64* __restrict__ ws,
    int n_points, int blocks_per_level, int stride_pts)
{
    int b     = blockIdx.x;
    int xcd   = b & 7;
    int j     = b >> 3;
    int phase = (j >= blocks_per_level) ? 1 : 0;
    int l     = xcd + (phase << 3);
    int jj    = j - phase * blocks_per_level;
    int base  = jj * 256 + (int)threadIdx.x;

    const u64* tbl = (const u64*)tables + ((size_t)l << LOG2_HASHMAP);
    u64* wsl = ws + (size_t)l * n_points;
    int shift = 15 - l;

    unsigned hh[PPT];
    int      nn[PPT];
    bool     ok[PPT];
#pragma unroll
    for (int s = 0; s < PPT; ++s) {
        int n = base + s * stride_pts;        // grid-stride: coalesced
        nn[s] = n;
        ok[s] = (n < n_points);
        int ncl = ok[s] ? n : 0;
        float x = xyz[ncl * 3 + 0];
        float y = xyz[ncl * 3 + 1];
        float z = xyz[ncl * 3 + 2];
        // (u32)(x*2^19) exact; >>(15-l) == trunc(x*16*2^l) (floor-nesting).
        unsigned wx = (unsigned)(x * 524288.0f) >> shift;
        unsigned wy = (unsigned)(y * 524288.0f) >> shift;
        unsigned wz = (unsigned)(z * 524288.0f) >> shift;
        // uint32 wraparound preserves low 19 bits of the int64 hash.
        hh[s] = (wx ^ (wy * 2654435761u) ^ (wz * 805459861u)) & (TABLE_SIZE - 1u);
    }

    u64 f[PPT];
#pragma unroll
    for (int s = 0; s < PPT; ++s)             // 8 independent gathers in flight
        f[s] = tbl[hh[s]];

#pragma unroll
    for (int s = 0; s < PPT; ++s)
        if (ok[s])
            __builtin_nontemporal_store(f[s], wsl + nn[s]);
}

// ---------------- Stage 2: transpose ws[16][N] -> out[N][16] ----------------
// 16B-vectorized both sides. Level-major LDS tile: 16B contiguous ds_writes
// (2-way conflict = free); store phase reads 2 rows per lane, bank pattern
// -> exactly 2 lanes/bank = free.
__global__ __launch_bounds__(256) void transpose_kernel(
    const u64* __restrict__ ws,
    u64* __restrict__ out,
    int n_points)
{
    __shared__ u64 tile[NUM_LEVELS][129];   // [level][point], +1 u64 pad
    int n0 = blockIdx.x * 128;

    for (int i = threadIdx.x; i < 64 * NUM_LEVELS; i += 256) {
        int l  = i >> 6;
        int np = (i & 63) << 1;
        int gn = n0 + np;
        u64 a = 0, bb = 0;
        if (gn + 1 < n_points) {
            u64x2 v = __builtin_nontemporal_load(
                (const u64x2*)(ws + (size_t)l * n_points + gn));
            a = v.x; bb = v.y;
        } else if (gn < n_points) {
            a = __builtin_nontemporal_load(ws + (size_t)l * n_points + gn);
        }
        tile[l][np]     = a;
        tile[l][np + 1] = bb;
    }
    __syncthreads();

    for (int i = threadIdx.x; i < 128 * (NUM_LEVELS / 2); i += 256) {
        int n  = i >> 3;
        int lp = i & 7;
        if (n0 + n < n_points) {
            u64x2 v;
            v.x = tile[2 * lp][n];
            v.y = tile[2 * lp + 1][n];
            __builtin_nontemporal_store(
                v, (u64x2*)(out + ((size_t)(n0 + n) * NUM_LEVELS + 2 * lp)));
        }
    }
}

// ---------------- Fallback (round-1 kernel) if ws too small ----------------
__global__ __launch_bounds__(256) void fused_kernel(
    const float* __restrict__ xyz,
    const float* __restrict__ tables,
    u64* __restrict__ out,
    int n_points)
{
    int tid = blockIdx.x * blockDim.x + threadIdx.x;
    int n = tid >> 4;
    int l = tid & 15;
    if (n >= n_points) return;
    float x = xyz[n * 3 + 0], y = xyz[n * 3 + 1], z = xyz[n * 3 + 2];
    float res = (float)(16u << l);
    unsigned ix = (unsigned)(x * res);
    unsigned iy = (unsigned)(y * res);
    unsigned iz = (unsigned)(z * res);
    unsigned h = (ix ^ (iy * 2654435761u) ^ (iz * 805459861u)) & (TABLE_SIZE - 1u);
    u64 f = *((const u64*)tables + (((size_t)l << LOG2_HASHMAP) + h));
    out[(size_t)n * NUM_LEVELS + l] = f;
}

extern "C" void kernel_launch(void* const* d_in, const int* in_sizes, int n_in,
                              void* d_out, int out_size, void* d_ws, size_t ws_size,
                              hipStream_t stream) {
    const float* xyz    = (const float*)d_in[0];
    const float* tables = (const float*)d_in[1];

    int n_points = in_sizes[0] / 3;
    size_t ws_main = (size_t)n_points * NUM_LEVELS * sizeof(u64);

    if (ws_size >= ws_main) {
        int blocks_per_level = (n_points + 256 * PPT - 1) / (256 * PPT);
        int stride_pts = blocks_per_level * 256;
        int grid1 = blocks_per_level * NUM_LEVELS;   // divisible by 8

        gather_kernel_xyz<<<grid1, 256, 0, stream>>>(
            xyz, tables, (u64*)d_ws, n_points, blocks_per_level, stride_pts);

        int grid2 = (n_points + 127) / 128;
        transpose_kernel<<<grid2, 256, 0, stream>>>(
            (const u64*)d_ws, (u64*)d_out, n_points);
    } else {
        int total = n_points * NUM_LEVELS;
        int grid = (total + 255) / 256;
        fused_kernel<<<grid, 256, 0, stream>>>(xyz, tables, (u64*)d_out, n_points);
    }
}